// Round 1
// 2965.344 us; speedup vs baseline: 1.2166x; 1.2166x over previous
//
#include <hip/hip_runtime.h>
#include <hip/hip_bf16.h>
#include <cstdint>
#include <type_traits>

// (B,N,D,H) = (32,1024,512,8). Inputs/outputs fp32; compute bf16 MFMA.
constexpr int B_SZ = 32;
constexpr int N_SZ = 1024;
constexpr int D_SZ = 512;
constexpr int H_SZ = 8;
constexpr int HD   = H_SZ * D_SZ;   // 4096

typedef __attribute__((ext_vector_type(8))) short short8;   // 8 x bf16
typedef __attribute__((ext_vector_type(4))) float floatx4;  // MFMA acc
typedef unsigned short u16;
typedef unsigned int   u32;

static __device__ __forceinline__ u16 f2bf(float f) {
    union { float f; unsigned int i; } c; c.f = f;
    unsigned int x = c.i;
    unsigned int r = x + 0x7FFFu + ((x >> 16) & 1u);  // RNE
    return (u16)(r >> 16);
}

// pack two f32 -> one u32 of 2 bf16 (lo = a, hi = b)
static __device__ __forceinline__ u32 cvt_pk_bf16(float a, float b) {
    u32 r;
    asm("v_cvt_pk_bf16_f32 %0, %1, %2" : "=v"(r) : "v"(a), "v"(b));
    return r;
}

// ---------------------------------------------------------------------------
__global__ void cvt_kernel(const float* __restrict__ src, u16* __restrict__ dst) {
    int idx = (blockIdx.x * 256 + threadIdx.x) * 4;
    float4 v = *(const float4*)(src + idx);
    ushort4 o;
    o.x = f2bf(v.x); o.y = f2bf(v.y); o.z = f2bf(v.z); o.w = f2bf(v.w);
    *(ushort4*)(dst + idx) = o;
}

// Wp[e][h*D+d] = bf16(Wo[e][d*H+h])
__global__ void woperm_kernel(const float* __restrict__ Wo, u16* __restrict__ Wp) {
    int idx = blockIdx.x * 256 + threadIdx.x;      // over 512*4096
    int e = idx >> 12;
    int c = idx & 4095;
    int d  = c & 511;
    int hh = c >> 9;
    Wp[idx] = f2bf(Wo[((size_t)e << 12) + d * H_SZ + hh]);
}

// ---------------------------------------------------------------------------
// GEMM: C = A[M,K] @ W[Nc,K]^T + bias. OM: 0 = bf16 row-major out,
// 1 = f32 row-major out, 2 = bf16 transposed-out vt[(row>>10)*HD+col][n].
// ---------------------------------------------------------------------------
template<typename AT, int OM>
__global__ __launch_bounds__(256, 2)
void gemm_bt(const AT* __restrict__ A, const u16* __restrict__ W,
             const float* __restrict__ bias, void* __restrict__ Cout,
             int M, int Nc, int K)
{
    __shared__ u16 Alds[128 * 40];
    __shared__ u16 Blds[128 * 40];
    const int tid  = threadIdx.x;
    const int lane = tid & 63;
    const int wave = tid >> 6;
    const int wm = wave >> 1, wn = wave & 1;
    const int m16 = lane & 15, quad = lane >> 4;
    const size_t tm0 = (size_t)blockIdx.x * 128;
    const size_t tn0 = (size_t)blockIdx.y * 128;

    floatx4 acc[4][4];
#pragma unroll
    for (int i = 0; i < 4; i++)
#pragma unroll
        for (int j = 0; j < 4; j++) acc[i][j] = (floatx4){0.f, 0.f, 0.f, 0.f};

    const int srow  = tid >> 1;
    const int skoff = (tid & 1) * 16;
    const AT*  ag = A + (tm0 + srow) * (size_t)K + skoff;
    const u16* bg = W + (tn0 + srow) * (size_t)K + skoff;

    for (int k0 = 0; k0 < K; k0 += 32) {
        short8 a0, a1;
        if constexpr (std::is_same_v<AT, float>) {
            float4 f0 = *(const float4*)(ag + k0);
            float4 f1 = *(const float4*)(ag + k0 + 4);
            float4 f2 = *(const float4*)(ag + k0 + 8);
            float4 f3 = *(const float4*)(ag + k0 + 12);
            a0 = (short8){(short)f2bf(f0.x), (short)f2bf(f0.y), (short)f2bf(f0.z), (short)f2bf(f0.w),
                          (short)f2bf(f1.x), (short)f2bf(f1.y), (short)f2bf(f1.z), (short)f2bf(f1.w)};
            a1 = (short8){(short)f2bf(f2.x), (short)f2bf(f2.y), (short)f2bf(f2.z), (short)f2bf(f2.w),
                          (short)f2bf(f3.x), (short)f2bf(f3.y), (short)f2bf(f3.z), (short)f2bf(f3.w)};
        } else {
            a0 = *(const short8*)(ag + k0);
            a1 = *(const short8*)(ag + k0 + 8);
        }
        short8 b0 = *(const short8*)(bg + k0);
        short8 b1 = *(const short8*)(bg + k0 + 8);
        __syncthreads();
        *(short8*)&Alds[srow * 40 + skoff]     = a0;
        *(short8*)&Alds[srow * 40 + skoff + 8] = a1;
        *(short8*)&Blds[srow * 40 + skoff]     = b0;
        *(short8*)&Blds[srow * 40 + skoff + 8] = b1;
        __syncthreads();
        short8 af[4], bf[4];
#pragma unroll
        for (int t = 0; t < 4; t++) {
            af[t] = *(const short8*)&Alds[(wm * 64 + t * 16 + m16) * 40 + quad * 8];
            bf[t] = *(const short8*)&Blds[(wn * 64 + t * 16 + m16) * 40 + quad * 8];
        }
#pragma unroll
        for (int i = 0; i < 4; i++)
#pragma unroll
            for (int j = 0; j < 4; j++)
                acc[i][j] = __builtin_amdgcn_mfma_f32_16x16x32_bf16(af[i], bf[j], acc[i][j], 0, 0, 0);
    }

#pragma unroll
    for (int j = 0; j < 4; j++) {
        int col = (int)tn0 + wn * 64 + j * 16 + m16;
        float bsv = bias[col];
#pragma unroll
        for (int i = 0; i < 4; i++) {
            size_t row = tm0 + wm * 64 + i * 16 + quad * 4;
            if constexpr (OM == 2) {
                int cloc = (int)(row >> 10);
                int n0   = (int)(row & 1023);
                ushort4 pk;
                pk.x = f2bf(acc[i][j][0] + bsv);
                pk.y = f2bf(acc[i][j][1] + bsv);
                pk.z = f2bf(acc[i][j][2] + bsv);
                pk.w = f2bf(acc[i][j][3] + bsv);
                u16* vtp = (u16*)Cout;
                *(ushort4*)&vtp[((size_t)cloc * HD + col) * N_SZ + n0] = pk;
            } else {
#pragma unroll
                for (int r = 0; r < 4; r++) {
                    if constexpr (OM == 1)
                        ((float*)Cout)[(row + r) * (size_t)Nc + col] = acc[i][j][r] + bsv;
                    else
                        ((u16*)Cout)[(row + r) * (size_t)Nc + col] = f2bf(acc[i][j][r] + bsv);
                }
            }
        }
    }
}

// ---------------------------------------------------------------------------
// Flash attention per (b,h). Q-tile 64, K/V j-tile 32, 4 waves.
//  v3 structure:
//  - swapped QK^T: S^T = mfma(K_frag, Q_frag) -> softmax row is lane-local
//    (q = m16); tile reduce = in-lane tree + shfl_xor(16,32). m,l scalar/lane.
//  - P (64q x 32k bf16) published to a Klds overlay; PV is block-cooperative:
//    wave w computes O[all 64 q][e-slice w*128..+127]. P-frags reused x8,
//    V-frags reused x4 -> PV LDS reads 12KB/wave-tile (was 32KB).
//  - defer-max (THR=8): rescale of acc only when tile max exceeds running
//    max by >8; alpha broadcast through LDS (acc rows span other waves' q).
//  - XCD-aware block swizzle: all 16 q-tiles of one (b,h) on one XCD ->
//    K/V prefetches hit L2/L3 instead of HBM.
//  Barriers/tile: [A] Kw [B] S..softmax [C1] Vw+Pw [C2] PV.
//  LDS 64KB total -> 2 blocks/CU.
// ---------------------------------------------------------------------------
__global__ __launch_bounds__(256, 2)
void attn_kernel(const u16* __restrict__ qh, const u16* __restrict__ kh,
                 const u16* __restrict__ vt, u16* __restrict__ ao)
{
    __shared__ u16 Klds[32 * 512];        // 32,768 B, swizzled: chunk c' = c ^ (row&7)
    __shared__ u16 Vtlds[512 * 32];       // 32,768 B, swizzled: c' = c ^ (e&3) ^ ((e>>2)&3)
    // overlays in Klds (valid between [C2] and next tile's K-write):
    u16*   Pov    = Klds;                 // P[64 q][40] bf16 (2560 u16)
    float* alphaF = (float*)&Klds[2560];  // alpha[64]   (byte 5120)
    float* lF     = (float*)&Klds[2688];  // l[64]       (byte 5376, epilogue only)
    u32*   flagp  = (u32*)&Klds[2816];    // flags[4]    (byte 5632)

    const int tid  = threadIdx.x;
    const int lane = tid & 63;
    const int wave = tid >> 6;
    const int m16  = lane & 15;
    const int quad = lane >> 4;

    // --- XCD-aware swizzle: hardware round-robins consecutive linear block
    // ids across the 8 XCDs; remap so XCD k gets a contiguous work chunk
    // (=> all q-tiles of a (b,h) share one XCD's L2). nwg = 128*Cc, %8==0.
    const int orig = blockIdx.x + ((int)blockIdx.y << 4) + ((int)blockIdx.z << 7);
    const int cpx  = ((int)gridDim.z << 7) >> 3;     // nwg/8
    const int swz  = (orig & 7) * cpx + (orig >> 3);
    const int qt = swz & 15;
    const int h  = (swz >> 4) & 7;
    const int bb = swz >> 7;

    // --- per-lane swizzled LDS addresses (constant across tiles) ---
    // K read (A-frag of S^T): row = s*16+m16, chunk c = kk*4+quad, c' = c ^ (m16&7)
    const int kxor = m16 & 7;
    const int qx8  = (quad ^ (kxor & 3)) * 8;          // elems
    const int kx32 = (kxor & 4) * 8;                   // elems (0 or 32)
    const u16* kaddrE = &Klds[m16 * 512 + qx8 + kx32]; // even kk: + kk*32
    const u16* kaddrO = &Klds[m16 * 512 + qx8 - kx32]; // odd  kk: + kk*32
    // Vt read (B-frag of PV): row e = ct*16+m16, chunk c = quad,
    // c' = quad^(m16&3)^((m16>>2)&3)
    const int vx8 = (quad ^ (m16 & 3) ^ ((m16 >> 2) & 3)) * 8;
    const u16* vaddr = &Vtlds[m16 * 32 + vx8];          // + ct*512 elems
    // Vt write: e = i*64 + wave*16 + (lane>>2), c = lane&3
    const int ebase = wave * 16 + (lane >> 2);
    const int cw8   = ((lane & 3) ^ ((lane >> 2) & 3) ^ ((lane >> 4) & 3)) * 8;

    // Q fragments in registers (B-operand of the swapped S^T MFMA;
    // B[col=q=m16][k-dim = e = kk*32 + quad*8 + j]) -- same layout as before.
    const int qrow = qt * 64 + wave * 16 + m16;
    const u16* qptr = qh + ((size_t)(bb * N_SZ + qrow)) * HD + h * D_SZ + quad * 8;
    short8 qfrag[16];
#pragma unroll
    for (int kk = 0; kk < 16; kk++)
        qfrag[kk] = *(const short8*)(qptr + kk * 32);

    // acc[j][qc]: O rows q = qc*16 + quad*4 + r, cols e = wave*128 + j*16 + m16
    floatx4 acc[8][4];
#pragma unroll
    for (int j = 0; j < 8; j++)
#pragma unroll
        for (int qc = 0; qc < 4; qc++) acc[j][qc] = (floatx4){0.f, 0.f, 0.f, 0.f};

    float mrow = -3.0e38f, lrow = 0.f;    // state for q = wave*16 + m16

    const float scale = 0.04419417382415922f;   // 1/sqrt(512)
    const u16* kbase  = kh + ((size_t)(bb * N_SZ)) * HD + h * D_SZ;
    const u16* vtbase = vt + ((size_t)bb * HD + h * D_SZ) * N_SZ;

    // prologue: prefetch K tile 0
    short8 kreg[8];
#pragma unroll
    for (int i = 0; i < 8; i++) {
        int row = i * 4 + wave;
        kreg[i] = *(const short8*)(kbase + (size_t)row * HD + lane * 8);
    }

    for (int kt = 0; kt < 32; kt++) {
        __syncthreads();                              // [A] prev PV (P+V reads) done
        // write K tile from prefetched regs (also restores overlay rows)
#pragma unroll
        for (int i = 0; i < 8; i++) {
            int row = i * 4 + wave;
            int cp  = lane ^ (row & 7);
            *(short8*)&Klds[row * 512 + cp * 8] = kreg[i];
        }
        __syncthreads();                              // [B]

        // issue V loads for this tile (consumed at [C1])
        short8 vreg[8];
#pragma unroll
        for (int i = 0; i < 8; i++) {
            int e = i * 64 + ebase;
            vreg[i] = *(const short8*)(vtbase + (size_t)e * N_SZ + kt * 32 + (lane & 3) * 8);
        }

        // ---- S^T = K Q^T : lane holds S[q=m16][k = quad*4+r (+16)] ----
        floatx4 s0a = (floatx4){0.f,0.f,0.f,0.f}, s0b = s0a, s1a = s0a, s1b = s0a;
        __builtin_amdgcn_s_setprio(1);
#pragma unroll
        for (int kk = 0; kk < 16; kk++) {
            const u16* p = (kk & 1) ? kaddrO : kaddrE;
            short8 kb0 = *(const short8*)(p + kk * 32);
            short8 kb1 = *(const short8*)(p + kk * 32 + 8192);
            if (kk & 1) {
                s0b = __builtin_amdgcn_mfma_f32_16x16x32_bf16(kb0, qfrag[kk], s0b, 0, 0, 0);
                s1b = __builtin_amdgcn_mfma_f32_16x16x32_bf16(kb1, qfrag[kk], s1b, 0, 0, 0);
            } else {
                s0a = __builtin_amdgcn_mfma_f32_16x16x32_bf16(kb0, qfrag[kk], s0a, 0, 0, 0);
                s1a = __builtin_amdgcn_mfma_f32_16x16x32_bf16(kb1, qfrag[kk], s1a, 0, 0, 0);
            }
        }
        __builtin_amdgcn_s_setprio(0);
        floatx4 s0 = s0a + s0b;
        floatx4 s1 = s1a + s1b;

        // ---- in-register online softmax (row q = m16, defer-max THR=8) ----
        float a[8];
#pragma unroll
        for (int r = 0; r < 4; r++) { a[r] = s0[r] * scale; a[4 + r] = s1[r] * scale; }
        float pm = fmaxf(fmaxf(fmaxf(a[0], a[1]), fmaxf(a[2], a[3])),
                         fmaxf(fmaxf(a[4], a[5]), fmaxf(a[6], a[7])));
        pm = fmaxf(pm, __shfl_xor(pm, 16, 64));
        pm = fmaxf(pm, __shfl_xor(pm, 32, 64));
        float alpha = 1.0f;
        u32 wflag = 0u;
        if (__any(pm > mrow + 8.0f)) {
            float mnew = fmaxf(mrow, pm);
            alpha = __expf(mrow - mnew);
            mrow = mnew;
            wflag = 1u;
        }
        float p[8];
        float ps = 0.f;
#pragma unroll
        for (int i = 0; i < 8; i++) { p[i] = __expf(a[i] - mrow); ps += p[i]; }
        ps += __shfl_xor(ps, 16, 64);
        ps += __shfl_xor(ps, 32, 64);
        lrow = lrow * alpha + ps;

        u32 w0 = cvt_pk_bf16(p[0], p[1]);   // k = quad*4 + 0,1
        u32 w1 = cvt_pk_bf16(p[2], p[3]);   // k = quad*4 + 2,3
        u32 w2 = cvt_pk_bf16(p[4], p[5]);   // k = 16 + quad*4 + 0,1
        u32 w3 = cvt_pk_bf16(p[6], p[7]);

        // prefetch K(t+1) (lands during PV + barriers)
        int ktn = (kt < 31) ? (kt + 1) : kt;
#pragma unroll
        for (int i = 0; i < 8; i++) {
            int row = i * 4 + wave;
            kreg[i] = *(const short8*)(kbase + (size_t)(ktn * 32 + row) * HD + lane * 8);
        }

        __syncthreads();                              // [C1] all S K-reads done

        // write V^T tile (vreg latency hidden by S+softmax)
#pragma unroll
        for (int i = 0; i < 8; i++) {
            int e = i * 64 + ebase;
            *(short8*)&Vtlds[e * 32 + cw8] = vreg[i];
        }
        // publish P into Klds overlay: P[q][k], stride 40 u16
        {
            int q40 = (wave * 16 + m16) * 40;
            uint2 lo; lo.x = w0; lo.y = w1;
            uint2 hi; hi.x = w2; hi.y = w3;
            *(uint2*)&Pov[q40 + quad * 4]      = lo;
            *(uint2*)&Pov[q40 + 16 + quad * 4] = hi;
        }
        if (quad == 0) alphaF[wave * 16 + m16] = alpha;
        if (lane == 0) flagp[wave] = wflag;
        __syncthreads();                              // [C2] P, alpha, V visible

        // conditional block-wide rescale (rare with defer-max)
        u32 f = flagp[0] | flagp[1] | flagp[2] | flagp[3];
        if (f) {
#pragma unroll
            for (int qc = 0; qc < 4; qc++) {
#pragma unroll
                for (int r = 0; r < 4; r++) {
                    float av = alphaF[qc * 16 + quad * 4 + r];
#pragma unroll
                    for (int j = 0; j < 8; j++) acc[j][qc][r] *= av;
                }
            }
        }

        // ---- PV: all 64 q, e-slice = wave*128 .. +127 ----
        short8 pf[4];
#pragma unroll
        for (int qc = 0; qc < 4; qc++)
            pf[qc] = *(const short8*)&Pov[(qc * 16 + m16) * 40 + quad * 8];
        __builtin_amdgcn_s_setprio(1);
#pragma unroll
        for (int j = 0; j < 8; j++) {
            short8 vf = *(const short8*)(vaddr + (wave * 8 + j) * 512);
#pragma unroll
            for (int qc = 0; qc < 4; qc++)
                acc[j][qc] = __builtin_amdgcn_mfma_f32_16x16x32_bf16(pf[qc], vf, acc[j][qc], 0, 0, 0);
        }
        __builtin_amdgcn_s_setprio(0);
    }

    // ---- epilogue: publish l, normalize, store ----
    if (quad == 0) lF[wave * 16 + m16] = lrow;        // disjoint from P region
    __syncthreads();
#pragma unroll
    for (int qc = 0; qc < 4; qc++) {
#pragma unroll
        for (int r = 0; r < 4; r++) {
            int row = qt * 64 + qc * 16 + quad * 4 + r;
            float invl = 1.0f / lF[qc * 16 + quad * 4 + r];
            size_t obase = ((size_t)(bb * N_SZ + row)) * HD + h * D_SZ + wave * 128;
#pragma unroll
            for (int j = 0; j < 8; j++)
                ao[obase + j * 16 + m16] = f2bf(acc[j][qc][r] * invl);
        }
    }
}

// ---------------------------------------------------------------------------
extern "C" void kernel_launch(void* const* d_in, const int* in_sizes, int n_in,
                              void* d_out, int out_size, void* d_ws, size_t ws_size,
                              hipStream_t stream)
{
    const float* kin = (const float*)d_in[0];
    const float* vin = (const float*)d_in[1];
    const float* qin = (const float*)d_in[2];
    const float* Wk  = (const float*)d_in[3];
    const float* bk  = (const float*)d_in[4];
    const float* Wv  = (const float*)d_in[5];
    const float* bv  = (const float*)d_in[6];
    const float* Wq  = (const float*)d_in[7];
    const float* bq  = (const float*)d_in[8];
    const float* Wo  = (const float*)d_in[9];
    const float* bo  = (const float*)d_in[10];
    float* out = (float*)d_out;

    u16* ws = (u16*)d_ws;
    const size_t wEl      = (size_t)H_SZ * D_SZ * D_SZ;  // 2M elems per W
    const size_t permEl   = (size_t)D_SZ * HD;           // 2M
    const size_t perBatch = (size_t)N_SZ * HD;           // 4M per buffer per batch
    const size_t fixedEl  = 3 * wEl + permEl;            // 8M
    long long availEl = (long long)(ws_size / 2) - (long long)fixedEl;
    int C = 1;
    if (availEl > 0) {
        long long c = availEl / (long long)(4 * perBatch);
        C = (int)(c < 1 ? 1 : (c > B_SZ ? B_SZ : c));
    }

    u16* wqb = ws;
    u16* wkb = wqb + wEl;
    u16* wvb = wkb + wEl;
    u16* wop = wvb + wEl;
    u16* qh  = wop + permEl;
    u16* khb = qh  + (size_t)C * perBatch;
    u16* vtb = khb + (size_t)C * perBatch;
    u16* ao  = vtb + (size_t)C * perBatch;

    const int cvtBlocks = (int)(wEl / 1024);
    cvt_kernel<<<cvtBlocks, 256, 0, stream>>>(Wq, wqb);
    cvt_kernel<<<cvtBlocks, 256, 0, stream>>>(Wk, wkb);
    cvt_kernel<<<cvtBlocks, 256, 0, stream>>>(Wv, wvb);
    woperm_kernel<<<(int)(permEl / 256), 256, 0, stream>>>(Wo, wop);

    for (int b0 = 0; b0 < B_SZ; b0 += C) {
        int Cc = (B_SZ - b0 < C) ? (B_SZ - b0) : C;
        int M = Cc * N_SZ;
        dim3 gp(M / 128, HD / 128);
        gemm_bt<float, 0><<<gp, 256, 0, stream>>>(qin + (size_t)b0 * N_SZ * D_SZ, wqb, bq, qh,  M, HD, D_SZ);
        gemm_bt<float, 0><<<gp, 256, 0, stream>>>(kin + (size_t)b0 * N_SZ * D_SZ, wkb, bk, khb, M, HD, D_SZ);
        gemm_bt<float, 2><<<gp, 256, 0, stream>>>(vin + (size_t)b0 * N_SZ * D_SZ, wvb, bv, vtb, M, HD, D_SZ);
        attn_kernel<<<dim3(N_SZ / 64, H_SZ, Cc), 256, 0, stream>>>(qh, khb, vtb, ao);
        gemm_bt<u16, 1><<<dim3(M / 128, D_SZ / 128), 256, 0, stream>>>(ao, wop, bo,
                                                                       out + (size_t)b0 * N_SZ * D_SZ, M, D_SZ, HD);
    }
}